// Round 5
// baseline (152.866 us; speedup 1.0000x reference)
//
#include <hip/hip_runtime.h>
#include <math.h>

#define K_TOT 32
#define K_IND 16
#define K_MLP 16
#define DHID  64
#define M_NODES 4
#define LOG2E 1.44269504088896340736f

__device__ __forceinline__ float fast_rcp(float x) {
    float r; asm("v_rcp_f32 %0, %1" : "=v"(r) : "v"(x)); return r;
}
__device__ __forceinline__ float fast_exp2(float x) {
    float r; asm("v_exp_f32 %0, %1" : "=v"(r) : "v"(x)); return r;
}

// ws layout (ints): P floats [0..16), N floats [16..32), flag @32,
// rp = ((int*)ws)+64, length N+1.

// Prep: block 0 lanes 0..63 compute collapsed-MLP constants
//   P_k = sum_{j: w1_j>0} w1_j*w2[j][k], N_k = sum_{j: w1_j<0} w1_j*w2[j][k]
// and flag = (all b1 == 0).
// rp via coalesced SCAN: thread e reads recv[e],recv[e+1] and writes
// rp[t]=e+1 for t in (recv[e], recv[e+1]]; thread 0 fills the head;
// tail handled by the r1=N sentinel.
__global__ void prep_kernel(const int* __restrict__ recv, int E, int N,
                            const float* __restrict__ w1,
                            const float* __restrict__ b1,
                            const float* __restrict__ w2,
                            float* __restrict__ wsP,
                            float* __restrict__ wsN,
                            int* __restrict__ wsflag,
                            int* __restrict__ rp) {
    if (blockIdx.x == 0 && threadIdx.x < 64) {
        int t = threadIdx.x;
        if (t < K_MLP) {
            float P = 0.f, Nn = 0.f;
            for (int j = 0; j < DHID; ++j) {
                float w = w1[j];
                float v = w2[j * K_MLP + t];
                P  += fmaxf(w, 0.f) * v;
                Nn += fminf(w, 0.f) * v;
            }
            wsP[t] = P; wsN[t] = Nn;
        }
        bool nz = (b1[t] != 0.f);
        unsigned long long mask = __ballot(nz);
        if (t == 0) *wsflag = (mask == 0ull) ? 1 : 0;
    }
    int e = blockIdx.x * blockDim.x + threadIdx.x;
    if (e < E) {
        int r0 = recv[e];
        int r1 = (e + 1 < E) ? recv[e + 1] : N;
        if (e == 0) {
            for (int t = 0; t <= r0; ++t) rp[t] = 0;
        }
        for (int t = r0 + 1; t <= r1; ++t) rp[t] = e + 1;
    }
}

// One wave per M_NODES=4 consecutive nodes. eg = lane>>4 (4 edge slots),
// cc = lane&15 (channel pair: indicator cc + mlp cc+16).
// Wave prologue: rp[n0..n0+4] lane-parallel + shfl; 4 node rows via 2
// coalesced 64-lane loads (nr extracted by shfl).
// Fast path (wave-level: all b1==0 && b==2 && max len<=64), per node k:
//  - node k+1's edge scalars prefetched before node k's group loop
//  - groups processed in 4-DEEP BATCHES: 12 shfl + 8 gather loads issued
//    back-to-back, then 4 group-computes (one latency wait per batch).
//    Over-issued groups: d=2.0 fails bins, valid-mask kills p, loads are
//    L1 dup-hits; compute skipped by wave-uniform (G<nG) ladder.
//  - softmax shift = bound M (d<=1), v_exp_f32; normalization via v_rcp_f32
// Phase B (shared epilogue): one w-read per j serves all 4 nodes; s_gn
// k-major [node][chan] -> conflict-free writes + broadcast reads; outputs
// as 2 coalesced 128-float stores.
__global__ __launch_bounds__(256) void graph_kernel(
        const float* __restrict__ nodes,
        const float* __restrict__ dist,
        const float* __restrict__ padv,
        const int*   __restrict__ send,
        const float* __restrict__ w1,
        const float* __restrict__ b1,
        const float* __restrict__ w2,
        const float* __restrict__ b2,
        const float* __restrict__ a_p,
        const float* __restrict__ b_p,
        const float* __restrict__ wg_self,
        const float* __restrict__ wg_gath,
        const float* __restrict__ bg,
        const float* __restrict__ wsP,
        const float* __restrict__ wsN,
        const int*   __restrict__ wsflag,
        const int*   __restrict__ rp,
        float* __restrict__ out,
        int N, int E) {
    __shared__ __align__(16) float2 s_wp[1024];       // [j*32+oc] = (Ws, Wg)
    __shared__ __align__(16) float2 s_gn[4][4][32];   // [wave][node k][chan j] = (n_j, g_j)

    // stage packed epilogue weights once per block
    {
        int t = threadIdx.x;
        float4 ws4 = ((const float4*)wg_self)[t];
        float4 wg4 = ((const float4*)wg_gath)[t];
        s_wp[t * 4 + 0] = make_float2(ws4.x, wg4.x);
        s_wp[t * 4 + 1] = make_float2(ws4.y, wg4.y);
        s_wp[t * 4 + 2] = make_float2(ws4.z, wg4.z);
        s_wp[t * 4 + 3] = make_float2(ws4.w, wg4.w);
    }
    __syncthreads();

    int wv   = threadIdx.x >> 6;
    int wave = blockIdx.x * 4 + wv;
    int n0   = wave * M_NODES;
    if (n0 >= N) return;

    int lane = threadIdx.x & 63;
    int eg   = lane >> 4;   // edge slot 0..3
    int cc   = lane & 15;   // channel pair index

    float a_c = fminf(fmaxf(a_p[0], 0.f), 1.f);
    float am  = 1.f - a_c;
    float bc  = fabsf(b_p[0]);

    float Pk = wsP[cc];
    float Nk = wsN[cc];
    float Pk2 = Pk * LOG2E;
    float Nk2 = Nk * LOG2E;
    float negM2 = -fmaxf(fabsf(Pk2), fabsf(Nk2));   // bound-M (d<=1), log2e-folded

    float lo = (float)cc * 0.0625f;
    float hi = lo + 0.0625f;

    int fastflag = (*wsflag != 0) && (bc == 2.0f);
    float bgv = bg[lane & 31];

    // rp[n0 .. n0+4] via one lane-parallel load + shfl broadcast
    int rl = rp[min(n0 + min(lane, 4), N)];
    int e0k[5];
#pragma unroll
    for (int k = 0; k < 5; ++k) e0k[k] = __shfl(rl, k);
    int lenk[4]; int maxlen = 0;
#pragma unroll
    for (int k = 0; k < 4; ++k) {
        lenk[k] = e0k[k + 1] - e0k[k];
        maxlen = max(maxlen, lenk[k]);
    }

    // all 4 node rows: 2 coalesced 64-lane loads (128 contiguous floats)
    int cap = N * K_TOT - 1;
    float rowA = nodes[min(n0 * K_TOT + lane, cap)];
    float rowB = nodes[min(n0 * K_TOT + 64 + lane, cap)];

    if (__builtin_amdgcn_readfirstlane((int)(fastflag && (maxlen <= 64)))) {
        // ---------------- FAST PATH (pipelined over 4 nodes) ----------------
        float dC, peC; int sC;
        {
            int li = min(lane, max(lenk[0] - 1, 0));
            int ei = min(e0k[0] + li, E - 1);
            dC = dist[ei]; sC = send[ei]; peC = padv[ei];
        }
#pragma unroll
        for (int k = 0; k < 4; ++k) {
            float dNx = 0.f, peNx = 0.f; int sNx = 0;
            if (k < 3) {   // issue next node's scalar loads before compute
                int li = min(lane, max(lenk[k + 1] - 1, 0));
                int ei = min(e0k[k + 1] + li, E - 1);
                dNx = dist[ei]; sNx = send[ei]; peNx = padv[ei];
            }
            int len = lenk[k];
            // invalid lanes: d=2.0 > DIST_MAX -> fails every bin check
            float d_all  = (lane < len) ? dC : 2.0f;
            int   s_all  = sC;
            float pe_all = peC;

            float nsrc = (k < 2) ? rowA : rowB;
            float nr0 = __shfl(nsrc, (k & 1) * 32 + cc);
            float nr1 = __shfl(nsrc, (k & 1) * 32 + cc + 16);
            float anr0 = a_c * nr0;
            float anr1 = a_c * nr1;

            float cnt = 0.f, si = 0.f, l = 0.f, acc = 0.f;
            if (len > 0) {
                int nG = (len + 3) >> 2;   // 1..16
                int nB = (nG + 3) >> 2;    // 1..4 batches of 4 groups

                for (int b = 0; b < nB; ++b) {
                    int G0 = b << 2;
                    float dl[4], pl[4], nsl0[4], nsl1[4];
                    bool  vl[4];
                    // batch-issue: 12 shfl + 8 gather loads, no compute between
#pragma unroll
                    for (int u = 0; u < 4; ++u) {
                        int i = ((G0 + u) << 2) + eg;   // <= 63 always
                        dl[u] = __shfl(d_all, i);
                        int s = __shfl(s_all, i);
                        pl[u] = __shfl(pe_all, i);
                        const float* nsrow = nodes + (s * K_TOT + cc);
                        nsl0[u] = nsrow[0];
                        nsl1[u] = nsrow[16];
                        vl[u] = i < len;
                    }
                    // batch compute; trailing dead groups skipped wave-uniformly
#pragma unroll
                    for (int u = 0; u < 4; ++u) {
                        if (G0 + u < nG) {
                            float t0 = fmaf(-am, nsl0[u], anr0);
                            float t1 = fmaf(-am, nsl1[u], anr1);
                            float pd0 = t0 * t0;
                            float pd1 = t1 * t1;
                            bool inb = (dl[u] > lo) && (dl[u] < hi);
                            cnt += inb ? 1.f : 0.f;
                            si   = inb ? fmaf(pl[u], pd0, si) : si;
                            float q2 = (dl[u] > 0.f) ? Pk2 : Nk2;
                            float p = fast_exp2(fmaf(dl[u], q2, negM2));
                            p = vl[u] ? p : 0.f;
                            l += p;
                            acc = fmaf(p, pl[u] * pd1, acc);
                        }
                    }
                }
            }

            // merge the 4 edge-slot partials (eg = lane bits 4,5)
#pragma unroll
            for (int off = 16; off <= 32; off <<= 1) {
                cnt += __shfl_xor(cnt, off);
                si  += __shfl_xor(si,  off);
                l   += __shfl_xor(l,   off);
                acc += __shfl_xor(acc, off);
            }
            float g_ind = si * fast_rcp(cnt + 1e-5f);
            float g_mlp = (l > 0.f) ? (acc * fast_rcp(l)) : 0.f;

            float pre_g = ((lane >> 4) & 1) ? g_mlp : g_ind;
            float pre_n = ((lane >> 4) & 1) ? nr1 : nr0;
            if (lane < 32) s_gn[wv][k][lane] = make_float2(pre_n, pre_g);

            dC = dNx; sC = sNx; peC = peNx;
        }
    } else {
        // ---------------- SLOW GENERIC PATH ----------------
        for (int k = 0; k < 4; ++k) {
            int len = lenk[k], e0 = e0k[k];
            float nsrc = (k < 2) ? rowA : rowB;
            float nr0 = __shfl(nsrc, (k & 1) * 32 + cc);
            float nr1 = __shfl(nsrc, (k & 1) * 32 + cc + 16);
            float anr0 = a_c * nr0;
            float anr1 = a_c * nr1;

            float cnt = 0.f, si = 0.f, l = 0.f, acc = 0.f;
            float m_on = -INFINITY;
            for (int i = eg; i < len; i += 4) {
                int e = e0 + i;
                float d  = dist[e];
                int   s  = send[e];
                float pe = padv[e];
                const float* nsrow = nodes + (s * K_TOT + cc);
                float ns0 = nsrow[0];
                float ns1 = nsrow[16];
                float t0 = fabsf(fmaf(-am, ns0, anr0));
                float t1 = fabsf(fmaf(-am, ns1, anr1));
                float pd0 = powf(t0, bc);
                float pd1 = powf(t1, bc);

                bool inb = (d > lo) && (d < hi);
                cnt += inb ? 1.f : 0.f;
                si  += inb ? pe * pd0 : 0.f;

                float mlp = 0.f;   // b2 cancels in the softmax ratio
                for (int j = 0; j < DHID; ++j) {
                    float h2 = fmaxf(fmaf(d, w1[j], b1[j]), 0.f);
                    mlp = fmaf(h2, w2[j * K_MLP + cc], mlp);
                }
                float mn = fmaxf(m_on, mlp);
                float al = (m_on == -INFINITY) ? 0.f : __expf(m_on - mn);
                float p  = __expf(mlp - mn);
                l   = fmaf(l, al, p);
                acc = fmaf(acc, al, p * pe * pd1);
                m_on = mn;
            }
#pragma unroll
            for (int off = 16; off <= 32; off <<= 1) {
                cnt += __shfl_xor(cnt, off);
                si  += __shfl_xor(si,  off);
                float m2 = __shfl_xor(m_on, off), l2 = __shfl_xor(l, off), a2 = __shfl_xor(acc, off);
                float mn = fmaxf(m_on, m2);
                float f1 = (m_on == -INFINITY) ? 0.f : __expf(m_on - mn);
                float f2 = (m2   == -INFINITY) ? 0.f : __expf(m2 - mn);
                l   = l * f1 + l2 * f2;
                acc = acc * f1 + a2 * f2;
                m_on = mn;
            }
            float g_ind = si / (cnt + 1e-5f);
            float g_mlp = (l > 0.f) ? (acc / l) : 0.f;

            float pre_g = ((lane >> 4) & 1) ? g_mlp : g_ind;
            float pre_n = ((lane >> 4) & 1) ? nr1 : nr0;
            if (lane < 32) s_gn[wv][k][lane] = make_float2(pre_n, pre_g);
        }
    }

    // ---------------- PHASE B: shared epilogue for all 4 nodes ----------------
    // one w-read per j serves 4 nodes; s_gn reads are lane-uniform broadcasts.
    int h  = lane >> 5;
    int oc = lane & 31;
    const float2* wpp   = &s_wp[(h * 16) * K_TOT + oc];
    const float2* gbase = &s_gn[wv][0][h * 16];

    float o0 = 0.f, o1 = 0.f, o2 = 0.f, o3 = 0.f;
#pragma unroll
    for (int jj = 0; jj < 16; ++jj) {
        float2 w  = wpp[jj * K_TOT];
        float2 v0 = gbase[0 * 32 + jj];
        float2 v1 = gbase[1 * 32 + jj];
        float2 v2 = gbase[2 * 32 + jj];
        float2 v3 = gbase[3 * 32 + jj];
        o0 = fmaf(v0.x, w.x, o0); o0 = fmaf(v0.y, w.y, o0);
        o1 = fmaf(v1.x, w.x, o1); o1 = fmaf(v1.y, w.y, o1);
        o2 = fmaf(v2.x, w.x, o2); o2 = fmaf(v2.y, w.y, o2);
        o3 = fmaf(v3.x, w.x, o3); o3 = fmaf(v3.y, w.y, o3);
    }
    o0 += __shfl_xor(o0, 32);
    o1 += __shfl_xor(o1, 32);
    o2 += __shfl_xor(o2, 32);
    o3 += __shfl_xor(o3, 32);
    o0 = fmaxf(o0 + bgv, 0.f);
    o1 = fmaxf(o1 + bgv, 0.f);
    o2 = fmaxf(o2 + bgv, 0.f);
    o3 = fmaxf(o3 + bgv, 0.f);

    // 2 coalesced 128-float stores (node = n0 + (lane>>5) [+2])
    float st0 = (lane >= 32) ? o1 : o0;
    float st1 = (lane >= 32) ? o3 : o2;
    int   b5  = lane >> 5;
    if (n0 + b5 < N)     out[n0 * K_TOT + lane]      = st0;
    if (n0 + 2 + b5 < N) out[n0 * K_TOT + 64 + lane] = st1;
}

extern "C" void kernel_launch(void* const* d_in, const int* in_sizes, int n_in,
                              void* d_out, int out_size, void* d_ws, size_t ws_size,
                              hipStream_t stream) {
    const float* nodes   = (const float*)d_in[0];
    const float* dist    = (const float*)d_in[1];
    const float* padv    = (const float*)d_in[2];
    const int*   recv    = (const int*)d_in[3];
    const int*   send    = (const int*)d_in[4];
    const float* w1      = (const float*)d_in[5];
    const float* b1      = (const float*)d_in[6];
    const float* w2      = (const float*)d_in[7];
    const float* b2      = (const float*)d_in[8];
    const float* a_p     = (const float*)d_in[9];
    const float* b_p     = (const float*)d_in[10];
    const float* wg_self = (const float*)d_in[11];
    const float* wg_gath = (const float*)d_in[12];
    const float* bg      = (const float*)d_in[13];
    float* out = (float*)d_out;

    int N = in_sizes[0] / K_TOT;
    int E = in_sizes[1];

    float* wsf    = (float*)d_ws;
    float* wsP    = wsf;
    float* wsN    = wsf + 16;
    int*   wsflag = (int*)d_ws + 32;
    int*   rp     = (int*)d_ws + 64;

    // scan-based rp needs a thread per edge
    prep_kernel<<<(E + 255) / 256, 256, 0, stream>>>(recv, E, N, w1, b1, w2,
                                                     wsP, wsN, wsflag, rp);
    int waves = (N + M_NODES - 1) / M_NODES;
    graph_kernel<<<(waves + 3) / 4, 256, 0, stream>>>(
        nodes, dist, padv, send, w1, b1, w2, b2, a_p, b_p,
        wg_self, wg_gath, bg, wsP, wsN, wsflag, rp, out, N, E);
}

// Round 6
// 144.491 us; speedup vs baseline: 1.0580x; 1.0580x over previous
//
#include <hip/hip_runtime.h>
#include <math.h>

#define K_TOT 32
#define K_IND 16
#define K_MLP 16
#define DHID  64
#define M_NODES 4
#define LOG2E 1.44269504088896340736f

template<bool B> struct BoolC { static constexpr bool value = B; };

__device__ __forceinline__ float fast_rcp(float x) {
    float r; asm("v_rcp_f32 %0, %1" : "=v"(r) : "v"(x)); return r;
}
__device__ __forceinline__ float fast_exp2(float x) {
    float r; asm("v_exp_f32 %0, %1" : "=v"(r) : "v"(x)); return r;
}

// ws layout (ints): P floats [0..16), N floats [16..32), flag @32, viol @33,
// rp = ((int*)ws)+64, length N+1. viol memset to 0 before prep.

// Prep: block 0 lanes 0..63 compute collapsed-MLP constants
//   P_k = sum_{j: w1_j>0} w1_j*w2[j][k], N_k = sum_{j: w1_j<0} w1_j*w2[j][k]
// and flag = (all b1 == 0). All threads: padv==1 check (wave __all, rare
// atomicOr on violation). rp via coalesced SCAN: thread e writes rp[t]=e+1
// for t in (recv[e], recv[e+1]]; thread 0 fills head; sentinel r1=N for tail.
__global__ void prep_kernel(const int* __restrict__ recv, int E, int N,
                            const float* __restrict__ w1,
                            const float* __restrict__ b1,
                            const float* __restrict__ w2,
                            const float* __restrict__ padv,
                            float* __restrict__ wsP,
                            float* __restrict__ wsN,
                            int* __restrict__ wsflag,
                            int* __restrict__ viol,
                            int* __restrict__ rp) {
    if (blockIdx.x == 0 && threadIdx.x < 64) {
        int t = threadIdx.x;
        if (t < K_MLP) {
            float P = 0.f, Nn = 0.f;
            for (int j = 0; j < DHID; ++j) {
                float w = w1[j];
                float v = w2[j * K_MLP + t];
                P  += fmaxf(w, 0.f) * v;
                Nn += fminf(w, 0.f) * v;
            }
            wsP[t] = P; wsN[t] = Nn;
        }
        bool nz = (b1[t] != 0.f);
        unsigned long long mask = __ballot(nz);
        if (t == 0) *wsflag = (mask == 0ull) ? 1 : 0;
    }
    int e = blockIdx.x * blockDim.x + threadIdx.x;
    bool ok = (e < E) ? (padv[e] == 1.0f) : true;
    if (!__all((int)ok)) {
        if ((threadIdx.x & 63) == 0) atomicOr(viol, 1);
    }
    if (e < E) {
        int r0 = recv[e];
        int r1 = (e + 1 < E) ? recv[e + 1] : N;
        if (e == 0) {
            for (int t = 0; t <= r0; ++t) rp[t] = 0;
        }
        for (int t = r0 + 1; t <= r1; ++t) rp[t] = e + 1;
    }
}

// One wave per M_NODES=4 consecutive nodes. eg = lane>>4 (4 edge slots),
// cc = lane&15 (channel pair: indicator cc + mlp cc+16).
// Wave prologue: rp[n0..n0+4] lane-parallel + shfl; 4 node rows via 2
// coalesced 64-lane loads (nr extracted by shfl).
// Fast path (wave-level: all b1==0 && b==2 && max len<=64), templated on
// ALLPAD (all edges_padding==1 -> no padv loads/shfls/muls at all):
//  - node k+1's edge scalars prefetched before node k's group loop
//  - sequential 2x-unrolled group loop (compiler schedules loads; explicit
//    batching measured slower in r5)
//  - softmax shift = bound M (d<=1), v_exp_f32; normalization via v_rcp_f32
// Phase B (shared epilogue): s_gn k-minor [j][node] -> per jj: 1 float2
// w-read + 2 float4 v-reads + 8 FMA; one w-read serves all 4 nodes;
// outputs as 2 coalesced 128-float stores.
__global__ __launch_bounds__(256) void graph_kernel(
        const float* __restrict__ nodes,
        const float* __restrict__ dist,
        const float* __restrict__ padv,
        const int*   __restrict__ send,
        const float* __restrict__ w1,
        const float* __restrict__ b1,
        const float* __restrict__ w2,
        const float* __restrict__ b2,
        const float* __restrict__ a_p,
        const float* __restrict__ b_p,
        const float* __restrict__ wg_self,
        const float* __restrict__ wg_gath,
        const float* __restrict__ bg,
        const float* __restrict__ wsP,
        const float* __restrict__ wsN,
        const int*   __restrict__ wsflag,
        const int*   __restrict__ viol,
        const int*   __restrict__ rp,
        float* __restrict__ out,
        int N, int E) {
    __shared__ __align__(16) float2 s_wp[1024];       // [j*32+oc] = (Ws, Wg)
    __shared__ __align__(16) float2 s_gn[4][32][4];   // [wave][chan j][node k]

    // stage packed epilogue weights once per block
    {
        int t = threadIdx.x;
        float4 ws4 = ((const float4*)wg_self)[t];
        float4 wg4 = ((const float4*)wg_gath)[t];
        s_wp[t * 4 + 0] = make_float2(ws4.x, wg4.x);
        s_wp[t * 4 + 1] = make_float2(ws4.y, wg4.y);
        s_wp[t * 4 + 2] = make_float2(ws4.z, wg4.z);
        s_wp[t * 4 + 3] = make_float2(ws4.w, wg4.w);
    }
    __syncthreads();

    int wv   = threadIdx.x >> 6;
    int wave = blockIdx.x * 4 + wv;
    int n0   = wave * M_NODES;
    if (n0 >= N) return;

    int lane = threadIdx.x & 63;
    int eg   = lane >> 4;   // edge slot 0..3
    int cc   = lane & 15;   // channel pair index

    float a_c = fminf(fmaxf(a_p[0], 0.f), 1.f);
    float am  = 1.f - a_c;
    float bc  = fabsf(b_p[0]);

    float Pk = wsP[cc];
    float Nk = wsN[cc];
    float Pk2 = Pk * LOG2E;
    float Nk2 = Nk * LOG2E;
    float negM2 = -fmaxf(fabsf(Pk2), fabsf(Nk2));   // bound-M (d<=1), log2e-folded

    float lo = (float)cc * 0.0625f;
    float hi = lo + 0.0625f;

    int fastflag = (*wsflag != 0) && (bc == 2.0f);
    int allpad   = (*viol == 0);
    float bgv = bg[lane & 31];

    // rp[n0 .. n0+4] via one lane-parallel load + shfl broadcast
    int rl = rp[min(n0 + min(lane, 4), N)];
    int e0k[5];
#pragma unroll
    for (int k = 0; k < 5; ++k) e0k[k] = __shfl(rl, k);
    int lenk[4]; int maxlen = 0;
#pragma unroll
    for (int k = 0; k < 4; ++k) {
        lenk[k] = e0k[k + 1] - e0k[k];
        maxlen = max(maxlen, lenk[k]);
    }

    // all 4 node rows: 2 coalesced 64-lane loads (128 contiguous floats)
    int cap = N * K_TOT - 1;
    float rowA = nodes[min(n0 * K_TOT + lane, cap)];
    float rowB = nodes[min(n0 * K_TOT + 64 + lane, cap)];

    // ---------------- FAST PATH (templated on ALLPAD) ----------------
    auto fast4 = [&](auto APC) {
        constexpr bool ALLPAD = decltype(APC)::value;
        float dC, peC = 1.f; int sC;
        {
            int li = min(lane, max(lenk[0] - 1, 0));
            int ei = min(e0k[0] + li, E - 1);
            dC = dist[ei]; sC = send[ei];
            if (!ALLPAD) peC = padv[ei];
        }
#pragma unroll
        for (int k = 0; k < 4; ++k) {
            float dNx = 0.f, peNx = 1.f; int sNx = 0;
            if (k < 3) {   // issue next node's scalar loads before compute
                int li = min(lane, max(lenk[k + 1] - 1, 0));
                int ei = min(e0k[k + 1] + li, E - 1);
                dNx = dist[ei]; sNx = send[ei];
                if (!ALLPAD) peNx = padv[ei];
            }
            int len = lenk[k];
            // invalid lanes: d=2.0 > DIST_MAX -> fails every bin check
            float d_all  = (lane < len) ? dC : 2.0f;
            int   s_all  = sC;
            float pe_all = peC;
            (void)pe_all;

            float nsrc = (k < 2) ? rowA : rowB;
            float nr0 = __shfl(nsrc, (k & 1) * 32 + cc);
            float nr1 = __shfl(nsrc, (k & 1) * 32 + cc + 16);
            float anr0 = a_c * nr0;
            float anr1 = a_c * nr1;

            float cnt = 0.f, si = 0.f, l = 0.f, acc = 0.f;
            if (len > 0) {
                int nG = (len + 3) >> 2;   // 1..16

#define GRP_BODY(G)                                                          \
                {                                                            \
                    int i = ((G) << 2) + eg;                                 \
                    bool valid = i < len;                                    \
                    float d  = __shfl(d_all, i);                             \
                    int   s  = __shfl(s_all, i);                             \
                    float pe = ALLPAD ? 1.0f : __shfl(pe_all, i);            \
                    const float* nsrow = nodes + (s * K_TOT + cc);           \
                    float ns0 = nsrow[0];                                    \
                    float ns1 = nsrow[16];                                   \
                    float t0 = fmaf(-am, ns0, anr0);                         \
                    float t1 = fmaf(-am, ns1, anr1);                         \
                    float pd0 = t0 * t0;                                     \
                    float pd1 = t1 * t1;                                     \
                    bool inb = (d > lo) && (d < hi);                         \
                    if (ALLPAD) {                                            \
                        float mb = inb ? 1.f : 0.f;                          \
                        cnt += mb;                                           \
                        si   = fmaf(mb, pd0, si);                            \
                    } else {                                                 \
                        cnt += inb ? 1.f : 0.f;                              \
                        si   = inb ? fmaf(pe, pd0, si) : si;                 \
                    }                                                        \
                    float q2 = (d > 0.f) ? Pk2 : Nk2;                        \
                    float p = fast_exp2(fmaf(d, q2, negM2));                 \
                    p = valid ? p : 0.f;                                     \
                    l += p;                                                  \
                    acc = ALLPAD ? fmaf(p, pd1, acc)                         \
                                 : fmaf(p, pe * pd1, acc);                   \
                }

                int g = 0;
                for (; g + 2 <= nG; g += 2) {
                    GRP_BODY(g)
                    GRP_BODY(g + 1)
                }
                if (g < nG) {
                    GRP_BODY(g)
                }
#undef GRP_BODY
            }

            // merge the 4 edge-slot partials (eg = lane bits 4,5)
#pragma unroll
            for (int off = 16; off <= 32; off <<= 1) {
                cnt += __shfl_xor(cnt, off);
                si  += __shfl_xor(si,  off);
                l   += __shfl_xor(l,   off);
                acc += __shfl_xor(acc, off);
            }
            float g_ind = si * fast_rcp(cnt + 1e-5f);
            float g_mlp = (l > 0.f) ? (acc * fast_rcp(l)) : 0.f;

            float pre_g = ((lane >> 4) & 1) ? g_mlp : g_ind;
            float pre_n = ((lane >> 4) & 1) ? nr1 : nr0;
            if (lane < 32) s_gn[wv][lane][k] = make_float2(pre_n, pre_g);

            dC = dNx; sC = sNx; peC = peNx;
        }
    };

    if (__builtin_amdgcn_readfirstlane((int)(fastflag && (maxlen <= 64)))) {
        if (__builtin_amdgcn_readfirstlane(allpad)) fast4(BoolC<true>{});
        else                                        fast4(BoolC<false>{});
    } else {
        // ---------------- SLOW GENERIC PATH ----------------
        for (int k = 0; k < 4; ++k) {
            int len = lenk[k], e0 = e0k[k];
            float nsrc = (k < 2) ? rowA : rowB;
            float nr0 = __shfl(nsrc, (k & 1) * 32 + cc);
            float nr1 = __shfl(nsrc, (k & 1) * 32 + cc + 16);
            float anr0 = a_c * nr0;
            float anr1 = a_c * nr1;

            float cnt = 0.f, si = 0.f, l = 0.f, acc = 0.f;
            float m_on = -INFINITY;
            for (int i = eg; i < len; i += 4) {
                int e = e0 + i;
                float d  = dist[e];
                int   s  = send[e];
                float pe = padv[e];
                const float* nsrow = nodes + (s * K_TOT + cc);
                float ns0 = nsrow[0];
                float ns1 = nsrow[16];
                float t0 = fabsf(fmaf(-am, ns0, anr0));
                float t1 = fabsf(fmaf(-am, ns1, anr1));
                float pd0 = powf(t0, bc);
                float pd1 = powf(t1, bc);

                bool inb = (d > lo) && (d < hi);
                cnt += inb ? 1.f : 0.f;
                si  += inb ? pe * pd0 : 0.f;

                float mlp = 0.f;   // b2 cancels in the softmax ratio
                for (int j = 0; j < DHID; ++j) {
                    float h2 = fmaxf(fmaf(d, w1[j], b1[j]), 0.f);
                    mlp = fmaf(h2, w2[j * K_MLP + cc], mlp);
                }
                float mn = fmaxf(m_on, mlp);
                float al = (m_on == -INFINITY) ? 0.f : __expf(m_on - mn);
                float p  = __expf(mlp - mn);
                l   = fmaf(l, al, p);
                acc = fmaf(acc, al, p * pe * pd1);
                m_on = mn;
            }
#pragma unroll
            for (int off = 16; off <= 32; off <<= 1) {
                cnt += __shfl_xor(cnt, off);
                si  += __shfl_xor(si,  off);
                float m2 = __shfl_xor(m_on, off), l2 = __shfl_xor(l, off), a2 = __shfl_xor(acc, off);
                float mn = fmaxf(m_on, m2);
                float f1 = (m_on == -INFINITY) ? 0.f : __expf(m_on - mn);
                float f2 = (m2   == -INFINITY) ? 0.f : __expf(m2 - mn);
                l   = l * f1 + l2 * f2;
                acc = acc * f1 + a2 * f2;
                m_on = mn;
            }
            float g_ind = si / (cnt + 1e-5f);
            float g_mlp = (l > 0.f) ? (acc / l) : 0.f;

            float pre_g = ((lane >> 4) & 1) ? g_mlp : g_ind;
            float pre_n = ((lane >> 4) & 1) ? nr1 : nr0;
            if (lane < 32) s_gn[wv][lane][k] = make_float2(pre_n, pre_g);
        }
    }

    // ---------------- PHASE B: shared epilogue for all 4 nodes ----------------
    // one w-read per j serves 4 nodes; v-reads: 2 x float4 broadcasts per jj.
    int h  = lane >> 5;
    int oc = lane & 31;
    const float2* wpp = &s_wp[(h * 16) * K_TOT + oc];
    const float2 (* __restrict__ sgw)[4] = s_gn[wv];

    float o0 = 0.f, o1 = 0.f, o2 = 0.f, o3 = 0.f;
#pragma unroll
    for (int jj = 0; jj < 16; ++jj) {
        float2 w   = wpp[jj * K_TOT];
        float4 v01 = *reinterpret_cast<const float4*>(&sgw[h * 16 + jj][0]);
        float4 v23 = *reinterpret_cast<const float4*>(&sgw[h * 16 + jj][2]);
        o0 = fmaf(v01.x, w.x, o0); o0 = fmaf(v01.y, w.y, o0);
        o1 = fmaf(v01.z, w.x, o1); o1 = fmaf(v01.w, w.y, o1);
        o2 = fmaf(v23.x, w.x, o2); o2 = fmaf(v23.y, w.y, o2);
        o3 = fmaf(v23.z, w.x, o3); o3 = fmaf(v23.w, w.y, o3);
    }
    o0 += __shfl_xor(o0, 32);
    o1 += __shfl_xor(o1, 32);
    o2 += __shfl_xor(o2, 32);
    o3 += __shfl_xor(o3, 32);
    o0 = fmaxf(o0 + bgv, 0.f);
    o1 = fmaxf(o1 + bgv, 0.f);
    o2 = fmaxf(o2 + bgv, 0.f);
    o3 = fmaxf(o3 + bgv, 0.f);

    // 2 coalesced 128-float stores (node = n0 + (lane>>5) [+2])
    float st0 = (lane >= 32) ? o1 : o0;
    float st1 = (lane >= 32) ? o3 : o2;
    int   b5  = lane >> 5;
    if (n0 + b5 < N)     out[n0 * K_TOT + lane]      = st0;
    if (n0 + 2 + b5 < N) out[n0 * K_TOT + 64 + lane] = st1;
}

extern "C" void kernel_launch(void* const* d_in, const int* in_sizes, int n_in,
                              void* d_out, int out_size, void* d_ws, size_t ws_size,
                              hipStream_t stream) {
    const float* nodes   = (const float*)d_in[0];
    const float* dist    = (const float*)d_in[1];
    const float* padv    = (const float*)d_in[2];
    const int*   recv    = (const int*)d_in[3];
    const int*   send    = (const int*)d_in[4];
    const float* w1      = (const float*)d_in[5];
    const float* b1      = (const float*)d_in[6];
    const float* w2      = (const float*)d_in[7];
    const float* b2      = (const float*)d_in[8];
    const float* a_p     = (const float*)d_in[9];
    const float* b_p     = (const float*)d_in[10];
    const float* wg_self = (const float*)d_in[11];
    const float* wg_gath = (const float*)d_in[12];
    const float* bg      = (const float*)d_in[13];
    float* out = (float*)d_out;

    int N = in_sizes[0] / K_TOT;
    int E = in_sizes[1];

    float* wsf    = (float*)d_ws;
    float* wsP    = wsf;
    float* wsN    = wsf + 16;
    int*   wsflag = (int*)d_ws + 32;
    int*   viol   = (int*)d_ws + 33;
    int*   rp     = (int*)d_ws + 64;

    hipMemsetAsync(viol, 0, sizeof(int), stream);

    // scan-based rp needs a thread per edge
    prep_kernel<<<(E + 255) / 256, 256, 0, stream>>>(recv, E, N, w1, b1, w2,
                                                     padv, wsP, wsN, wsflag,
                                                     viol, rp);
    int waves = (N + M_NODES - 1) / M_NODES;
    graph_kernel<<<(waves + 3) / 4, 256, 0, stream>>>(
        nodes, dist, padv, send, w1, b1, w2, b2, a_p, b_p,
        wg_self, wg_gath, bg, wsP, wsN, wsflag, viol, rp, out, N, E);
}